// Round 2
// baseline (616.121 us; speedup 1.0000x reference)
//
#include <hip/hip_runtime.h>
#include <hip/hip_bf16.h>
#include <math.h>

#define DD 64
#define NPB 2048          // nodes per batch (N)
#define RTOT 65536        // total node rows B*N

typedef __bf16 bf16;
typedef float f32x4 __attribute__((ext_vector_type(4)));

// Compiler-level memory fence: prevents reordering of LDS ops around the
// wave-synchronous write->read pattern. HW executes a wave's DS ops in order.
#define COMPILER_FENCE() asm volatile("" ::: "memory")

__device__ __forceinline__ float gelu_exact(float x) {
  return 0.5f * x * (1.0f + erff(x * 0.70710678118654752f));
}

// ---------------- embedding + patch mean ----------------
__global__ void __launch_bounds__(256) k_embed(const int* __restrict__ x,
                                               const float* __restrict__ emb,
                                               float* __restrict__ h) {
  int gid = blockIdx.x * 256 + threadIdx.x;   // grid covers RTOT*64 exactly
  int row = gid >> 6, d = gid & 63;
  const int* xp = x + row * 4;
  float s = 0.f;
#pragma unroll
  for (int p = 0; p < 4; ++p) s += emb[xp[p] * DD + d];
  h[row * DD + d] = s * 0.25f;
}

// ---------------- one message-passing round (simple f32 VALU) ----------------
// Block = 256 threads = 4 waves. Wave wv owns nodes [blk*64 + wv*16, +16).
// Lane j owns output dim j for every GEMM. Per-wave private LDS buffer X:
//   X[0:64]=h, X[64:128]=left, X[128:192]=gelu intermediates, X[192:256]=msgs.
// Weights staged to LDS as bf16 (48 KB); all accumulation/h-path in f32.
__global__ void __launch_bounds__(256) k_round_s(const float* __restrict__ hin,
                                                 float* __restrict__ hout,
                                                 const float* __restrict__ wm1,
                                                 const float* __restrict__ bm1,
                                                 const float* __restrict__ wm2,
                                                 const float* __restrict__ bm2,
                                                 const float* __restrict__ wu1,
                                                 const float* __restrict__ bu1,
                                                 const float* __restrict__ wu2,
                                                 const float* __restrict__ bu2,
                                                 const float* __restrict__ lng,
                                                 const float* __restrict__ lnb) {
  __shared__ bf16 Wm1s[128 * 64];   // [k][j] same layout as global
  __shared__ bf16 Wm2s[64 * 64];
  __shared__ bf16 Wu1s[128 * 64];
  __shared__ bf16 Wu2s[64 * 64];
  __shared__ float Xb[4][256];      // per-wave scratch

  const int tid = threadIdx.x;
  const int lane = tid & 63;
  const int wv = tid >> 6;

  for (int i = tid; i < 8192; i += 256) {
    Wm1s[i] = (bf16)wm1[i];
    Wu1s[i] = (bf16)wu1[i];
  }
  for (int i = tid; i < 4096; i += 256) {
    Wm2s[i] = (bf16)wm2[i];
    Wu2s[i] = (bf16)wu2[i];
  }
  const float bm1v = bm1[lane], bm2v = bm2[lane];
  const float bu1v = bu1[lane], bu2v = bu2[lane];
  const float lngv = lng[lane], lnbv = lnb[lane];
  __syncthreads();

  float* X = Xb[wv];

  for (int nn = 0; nn < 16; ++nn) {
    const int node = blockIdx.x * 64 + wv * 16 + nn;

    const float hj = hin[node * DD + lane];
    float lv = 0.f;
    if ((node & (NPB - 1)) != 0) lv = hin[(node - 1) * DD + lane];
    X[lane] = hj;
    X[64 + lane] = lv;
    COMPILER_FENCE();

    // msg_net layer 1: z = [h,left] @ wm1 + bm1 ; g = gelu(z)
    float a = bm1v;
#pragma unroll 8
    for (int k = 0; k < 128; ++k) a += X[k] * (float)Wm1s[k * 64 + lane];
    float g = gelu_exact(a);
    X[128 + lane] = g;
    COMPILER_FENCE();

    // msg_net layer 2: msgs = g @ wm2 + bm2
    float m = bm2v;
#pragma unroll 8
    for (int k = 0; k < 64; ++k) m += X[128 + k] * (float)Wm2s[k * 64 + lane];
    X[192 + lane] = m;
    COMPILER_FENCE();

    // update_net layer 1: zu = [h,msgs] @ wu1 + bu1 ; gu = gelu(zu)
    float zu = bu1v;
#pragma unroll 8
    for (int k = 0; k < 64; ++k) zu += X[k] * (float)Wu1s[k * 64 + lane];
#pragma unroll 8
    for (int k = 0; k < 64; ++k) zu += X[192 + k] * (float)Wu1s[(64 + k) * 64 + lane];
    float gu = gelu_exact(zu);
    COMPILER_FENCE();              // GEMM2's reads of X[128..192) are done (in-order wave)
    X[128 + lane] = gu;
    COMPILER_FENCE();

    // update_net layer 2: upd = gu @ wu2 + bu2
    float u = bu2v;
#pragma unroll 8
    for (int k = 0; k < 64; ++k) u += X[128 + k] * (float)Wu2s[k * 64 + lane];

    // residual + LayerNorm across the 64 lanes (full f32)
    const float xval = hj + u;
    float s1 = xval, s2 = xval * xval;
#pragma unroll
    for (int off = 1; off < 64; off <<= 1) {
      s1 += __shfl_xor(s1, off);
      s2 += __shfl_xor(s2, off);
    }
    const float mu = s1 * 0.015625f;
    const float var = s2 * 0.015625f - mu * mu;
    const float rstd = rsqrtf(var + 1e-5f);
    hout[node * DD + lane] = (xval - mu) * rstd * lngv + lnbv;
  }
}

// ---------------- readout: per-node logits, replicated x4 ----------------
// Block = 256 threads = 4 waves, 64 nodes/block. Lane owns 4 vocab entries.
// h row read via lane-uniform global loads (SGPR broadcast); w_r staged bf16.
__global__ void __launch_bounds__(256) k_readout(const float* __restrict__ h,
                                                 const float* __restrict__ wr,
                                                 const float* __restrict__ br,
                                                 float* __restrict__ out) {
  __shared__ bf16 Ws[64 * 256];   // [k][v], 32 KB
  const int tid = threadIdx.x, lane = tid & 63, wv = tid >> 6;
  for (int i = tid; i < 16384; i += 256) Ws[i] = (bf16)wr[i];
  const float brv0 = br[lane * 4 + 0], brv1 = br[lane * 4 + 1];
  const float brv2 = br[lane * 4 + 2], brv3 = br[lane * 4 + 3];
  __syncthreads();

  const int node0 = blockIdx.x * 64 + wv * 16;
  for (int nn = 0; nn < 16; ++nn) {
    const int node = node0 + nn;
    const float* __restrict__ hrow = h + (size_t)node * DD;
    float a0 = brv0, a1 = brv1, a2 = brv2, a3 = brv3;
#pragma unroll 8
    for (int k = 0; k < 64; ++k) {
      const float hk = hrow[k];            // lane-uniform -> scalar broadcast
      const bf16* wp = &Ws[k * 256 + lane * 4];
      a0 += hk * (float)wp[0];
      a1 += hk * (float)wp[1];
      a2 += hk * (float)wp[2];
      a3 += hk * (float)wp[3];
    }
    f32x4 o = {a0, a1, a2, a3};
    float* ob = out + (size_t)node * 1024 + lane * 4;   // 4 token rows contiguous
#pragma unroll
    for (int rep = 0; rep < 4; ++rep)
      *reinterpret_cast<f32x4*>(ob + rep * 256) = o;
  }
}

extern "C" void kernel_launch(void* const* d_in, const int* in_sizes, int n_in,
                              void* d_out, int out_size, void* d_ws, size_t ws_size,
                              hipStream_t stream) {
  const int*   x   = (const int*)d_in[0];
  const float* emb = (const float*)d_in[1];
  const float* wm1 = (const float*)d_in[2];
  const float* bm1 = (const float*)d_in[3];
  const float* wm2 = (const float*)d_in[4];
  const float* bm2 = (const float*)d_in[5];
  const float* wu1 = (const float*)d_in[6];
  const float* bu1 = (const float*)d_in[7];
  const float* wu2 = (const float*)d_in[8];
  const float* bu2 = (const float*)d_in[9];
  const float* lng = (const float*)d_in[10];
  const float* lnb = (const float*)d_in[11];
  const float* wr  = (const float*)d_in[12];
  const float* br  = (const float*)d_in[13];
  float* out = (float*)d_out;

  char* ws = (char*)d_ws;
  float* ha = (float*)ws;                                   // 16 MB
  float* hb = (float*)(ws + (size_t)RTOT * DD * 4);         // 16 MB

  hipLaunchKernelGGL(k_embed, dim3(16384), dim3(256), 0, stream, x, emb, ha);
  hipLaunchKernelGGL(k_round_s, dim3(1024), dim3(256), 0, stream,
                     ha, hb, wm1, bm1, wm2, bm2, wu1, bu1, wu2, bu2, lng, lnb);
  hipLaunchKernelGGL(k_round_s, dim3(1024), dim3(256), 0, stream,
                     hb, ha, wm1, bm1, wm2, bm2, wu1, bu1, wu2, bu2, lng, lnb);
  hipLaunchKernelGGL(k_round_s, dim3(1024), dim3(256), 0, stream,
                     ha, hb, wm1, bm1, wm2, bm2, wu1, bu1, wu2, bu2, lng, lnb);
  hipLaunchKernelGGL(k_readout, dim3(1024), dim3(256), 0, stream, hb, wr, br, out);
}

// Round 3
// 155.316 us; speedup vs baseline: 3.9669x; 3.9669x over previous
//
#include <hip/hip_runtime.h>
#include <hip/hip_bf16.h>
#include <math.h>

#define DD 64
#define NPB 2048          // nodes per batch (N)
#define RTOT 65536        // total node rows B*N
#define W1S 136           // padded row stride for [64][128] tiles (bank-spread)
#define W2S 72            // padded row stride for [64][64] tiles

typedef __bf16 bf16;
typedef bf16 bf16x8 __attribute__((ext_vector_type(8)));
typedef float f32x4 __attribute__((ext_vector_type(4)));

#define COMPILER_FENCE() asm volatile("" ::: "memory")

__device__ __forceinline__ f32x4 mfma16(bf16x8 a, bf16x8 b, f32x4 c) {
  return __builtin_amdgcn_mfma_f32_16x16x32_bf16(a, b, c, 0, 0, 0);
}

__device__ __forceinline__ float gelu_exact(float x) {
  return 0.5f * x * (1.0f + erff(x * 0.70710678118654752f));
}

// load 8 consecutive f32, convert to bf16x8 (RNE via cast)
__device__ __forceinline__ bf16x8 cvt8(const float* p) {
  f32x4 a = *reinterpret_cast<const f32x4*>(p);
  f32x4 b = *reinterpret_cast<const f32x4*>(p + 4);
  bf16x8 r;
  r[0] = (bf16)a[0]; r[1] = (bf16)a[1]; r[2] = (bf16)a[2]; r[3] = (bf16)a[3];
  r[4] = (bf16)b[0]; r[5] = (bf16)b[1]; r[6] = (bf16)b[2]; r[7] = (bf16)b[3];
  return r;
}

__device__ __forceinline__ bf16x8 zero8() {
  bf16x8 z = {(bf16)0.f, (bf16)0.f, (bf16)0.f, (bf16)0.f,
              (bf16)0.f, (bf16)0.f, (bf16)0.f, (bf16)0.f};
  return z;
}

// ---------------- embedding + patch mean ----------------
__global__ void __launch_bounds__(256) k_embed(const int* __restrict__ x,
                                               const float* __restrict__ emb,
                                               float* __restrict__ h) {
  int gid = blockIdx.x * 256 + threadIdx.x;   // grid covers RTOT*64 exactly
  int row = gid >> 6, d = gid & 63;
  const int* xp = x + row * 4;
  float s = 0.f;
#pragma unroll
  for (int p = 0; p < 4; ++p) s += emb[xp[p] * DD + d];
  h[row * DD + d] = s * 0.25f;
}

// ---------------- one message-passing round (MFMA) ----------------
// Block = 256 threads = 4 waves; 64 node rows/block, wave wv owns rows
// [wv*16, wv*16+16). All inter-GEMM LDS deps are within-wave (in-order DS).
// Weights converted f32->bf16 and transposed to [n][k] in LDS at block start;
// the [64][128] W1 buffer is time-shared: wm1 for GEMMs 1-2, wu1 for 3-4.
__global__ void __launch_bounds__(256) k_round_m(const float* __restrict__ hin,
                                                 float* __restrict__ hout,
                                                 const float* __restrict__ wm1,
                                                 const float* __restrict__ bm1,
                                                 const float* __restrict__ wm2,
                                                 const float* __restrict__ bm2,
                                                 const float* __restrict__ wu1,
                                                 const float* __restrict__ bu1,
                                                 const float* __restrict__ wu2,
                                                 const float* __restrict__ bu2,
                                                 const float* __restrict__ lng,
                                                 const float* __restrict__ lnb) {
  __shared__ bf16 W1[64 * W1S];    // [n][k] of wm1, later wu1 (17408 B)
  __shared__ bf16 W2m[64 * W2S];   // [n][k] of wm2 (9216 B)
  __shared__ bf16 W2u[64 * W2S];   // [n][k] of wu2
  __shared__ bf16 Ms[64 * W2S];    // msgs, block-local rows
  __shared__ bf16 Hs[64 * W2S];    // GELU intermediates

  const int tid = threadIdx.x;
  const int lane = tid & 63;
  const int wv = tid >> 6;
  const int l15 = lane & 15;
  const int lhi = lane >> 4;
  const int rowbase = blockIdx.x * 64;

  // ---- stage weights (coalesced global read, transposed LDS write) ----
  for (int i = tid; i < 8192; i += 256) {
    int k = i >> 6, n = i & 63;
    W1[n * W1S + k] = (bf16)wm1[i];
  }
  for (int i = tid; i < 4096; i += 256) {
    int k = i >> 6, n = i & 63;
    W2m[n * W2S + k] = (bf16)wm2[i];
    W2u[n * W2S + k] = (bf16)wu2[i];
  }
  float bm1v[4], bm2v[4], bu1v[4], bu2v[4], lngv[4], lnbv[4];
#pragma unroll
  for (int ct = 0; ct < 4; ++ct) {
    int c = ct * 16 + l15;
    bm1v[ct] = bm1[c]; bm2v[ct] = bm2[c];
    bu1v[ct] = bu1[c]; bu2v[ct] = bu2[c];
    lngv[ct] = lng[c]; lnbv[ct] = lnb[c];
  }
  __syncthreads();

  const int lrow = wv * 16 + l15;       // A-row (block-local)
  const int grow = rowbase + lrow;      // global node row
  const float* hrow = hin + (size_t)grow * DD;

  // A-fragments of h and left (live across GEMM1 and GEMM3)
  bf16x8 ah0 = cvt8(hrow + lhi * 8);
  bf16x8 ah1 = cvt8(hrow + 32 + lhi * 8);
  bf16x8 al0 = zero8(), al1 = zero8();
  if ((grow & (NPB - 1)) != 0) {
    al0 = cvt8(hrow - DD + lhi * 8);
    al1 = cvt8(hrow - DD + 32 + lhi * 8);
  }

  f32x4 acc[4];
  const f32x4 fz = {0.f, 0.f, 0.f, 0.f};

  // ======== GEMM1: [h,left] @ wm1 (K=128) -> GELU -> Hs ========
#pragma unroll
  for (int ct = 0; ct < 4; ++ct) acc[ct] = fz;
#pragma unroll
  for (int ct = 0; ct < 4; ++ct) {
    const bf16* wb = &W1[(ct * 16 + l15) * W1S];
    acc[ct] = mfma16(ah0, *reinterpret_cast<const bf16x8*>(wb + lhi * 8), acc[ct]);
    acc[ct] = mfma16(ah1, *reinterpret_cast<const bf16x8*>(wb + 32 + lhi * 8), acc[ct]);
    acc[ct] = mfma16(al0, *reinterpret_cast<const bf16x8*>(wb + 64 + lhi * 8), acc[ct]);
    acc[ct] = mfma16(al1, *reinterpret_cast<const bf16x8*>(wb + 96 + lhi * 8), acc[ct]);
  }
#pragma unroll
  for (int ct = 0; ct < 4; ++ct)
#pragma unroll
    for (int r = 0; r < 4; ++r) {
      float g = gelu_exact(acc[ct][r] + bm1v[ct]);
      Hs[(wv * 16 + lhi * 4 + r) * W2S + ct * 16 + l15] = (bf16)g;  // own rows
    }
  COMPILER_FENCE();

  // ======== GEMM2: g @ wm2 (K=64) -> msgs -> Ms ========
#pragma unroll
  for (int ct = 0; ct < 4; ++ct) acc[ct] = fz;
  {
    bf16x8 g0 = *reinterpret_cast<const bf16x8*>(&Hs[lrow * W2S + lhi * 8]);
    bf16x8 g1 = *reinterpret_cast<const bf16x8*>(&Hs[lrow * W2S + 32 + lhi * 8]);
#pragma unroll
    for (int ct = 0; ct < 4; ++ct) {
      const bf16* wb = &W2m[(ct * 16 + l15) * W2S];
      acc[ct] = mfma16(g0, *reinterpret_cast<const bf16x8*>(wb + lhi * 8), acc[ct]);
      acc[ct] = mfma16(g1, *reinterpret_cast<const bf16x8*>(wb + 32 + lhi * 8), acc[ct]);
    }
  }
#pragma unroll
  for (int ct = 0; ct < 4; ++ct)
#pragma unroll
    for (int r = 0; r < 4; ++r)
      Ms[(wv * 16 + lhi * 4 + r) * W2S + ct * 16 + l15] =
          (bf16)(acc[ct][r] + bm2v[ct]);
  COMPILER_FENCE();

  // ---- swap W1 contents: wm1 -> wu1 ----
  __syncthreads();
  for (int i = tid; i < 8192; i += 256) {
    int k = i >> 6, n = i & 63;
    W1[n * W1S + k] = (bf16)wu1[i];
  }
  __syncthreads();

  // ======== GEMM3: [h,msgs] @ wu1 (K=128) -> GELU -> Hs ========
#pragma unroll
  for (int ct = 0; ct < 4; ++ct) acc[ct] = fz;
  {
    bf16x8 m0 = *reinterpret_cast<const bf16x8*>(&Ms[lrow * W2S + lhi * 8]);
    bf16x8 m1 = *reinterpret_cast<const bf16x8*>(&Ms[lrow * W2S + 32 + lhi * 8]);
#pragma unroll
    for (int ct = 0; ct < 4; ++ct) {
      const bf16* wb = &W1[(ct * 16 + l15) * W1S];
      acc[ct] = mfma16(ah0, *reinterpret_cast<const bf16x8*>(wb + lhi * 8), acc[ct]);
      acc[ct] = mfma16(ah1, *reinterpret_cast<const bf16x8*>(wb + 32 + lhi * 8), acc[ct]);
      acc[ct] = mfma16(m0, *reinterpret_cast<const bf16x8*>(wb + 64 + lhi * 8), acc[ct]);
      acc[ct] = mfma16(m1, *reinterpret_cast<const bf16x8*>(wb + 96 + lhi * 8), acc[ct]);
    }
  }
  COMPILER_FENCE();
#pragma unroll
  for (int ct = 0; ct < 4; ++ct)
#pragma unroll
    for (int r = 0; r < 4; ++r) {
      float g = gelu_exact(acc[ct][r] + bu1v[ct]);
      Hs[(wv * 16 + lhi * 4 + r) * W2S + ct * 16 + l15] = (bf16)g;
    }
  COMPILER_FENCE();

  // ======== GEMM4: gu @ wu2 (K=64) -> upd; residual + LN ========
#pragma unroll
  for (int ct = 0; ct < 4; ++ct) acc[ct] = fz;
  {
    bf16x8 u0 = *reinterpret_cast<const bf16x8*>(&Hs[lrow * W2S + lhi * 8]);
    bf16x8 u1 = *reinterpret_cast<const bf16x8*>(&Hs[lrow * W2S + 32 + lhi * 8]);
#pragma unroll
    for (int ct = 0; ct < 4; ++ct) {
      const bf16* wb = &W2u[(ct * 16 + l15) * W2S];
      acc[ct] = mfma16(u0, *reinterpret_cast<const bf16x8*>(wb + lhi * 8), acc[ct]);
      acc[ct] = mfma16(u1, *reinterpret_cast<const bf16x8*>(wb + 32 + lhi * 8), acc[ct]);
    }
  }

  float xv[4][4];
#pragma unroll
  for (int ct = 0; ct < 4; ++ct)
#pragma unroll
    for (int r = 0; r < 4; ++r) {
      int row = rowbase + wv * 16 + lhi * 4 + r;
      xv[ct][r] = acc[ct][r] + bu2v[ct] + hin[row * DD + ct * 16 + l15];
    }
  float s1[4], s2[4];
#pragma unroll
  for (int r = 0; r < 4; ++r) {
    s1[r] = 0.f; s2[r] = 0.f;
#pragma unroll
    for (int ct = 0; ct < 4; ++ct) {
      s1[r] += xv[ct][r];
      s2[r] += xv[ct][r] * xv[ct][r];
    }
  }
#pragma unroll
  for (int off = 1; off < 16; off <<= 1)
#pragma unroll
    for (int r = 0; r < 4; ++r) {    // reduce across the 16 lanes sharing lhi
      s1[r] += __shfl_xor(s1[r], off);
      s2[r] += __shfl_xor(s2[r], off);
    }
#pragma unroll
  for (int r = 0; r < 4; ++r) {
    float mu = s1[r] * 0.015625f;
    float var = s2[r] * 0.015625f - mu * mu;
    float rstd = rsqrtf(var + 1e-5f);
    int row = rowbase + wv * 16 + lhi * 4 + r;
#pragma unroll
    for (int ct = 0; ct < 4; ++ct)
      hout[row * DD + ct * 16 + l15] =
          (xv[ct][r] - mu) * rstd * lngv[ct] + lnbv[ct];
  }
}

// ---------------- readout: per-node logits, replicated x4 ----------------
__global__ void __launch_bounds__(256) k_readout(const float* __restrict__ h,
                                                 const float* __restrict__ wr,
                                                 const float* __restrict__ br,
                                                 float* __restrict__ out) {
  __shared__ bf16 Ws[64 * 256];   // [k][v], 32 KB
  const int tid = threadIdx.x, lane = tid & 63, wv = tid >> 6;
  for (int i = tid; i < 16384; i += 256) Ws[i] = (bf16)wr[i];
  const float brv0 = br[lane * 4 + 0], brv1 = br[lane * 4 + 1];
  const float brv2 = br[lane * 4 + 2], brv3 = br[lane * 4 + 3];
  __syncthreads();

  const int node0 = blockIdx.x * 64 + wv * 16;
  for (int nn = 0; nn < 16; ++nn) {
    const int node = node0 + nn;
    const float* __restrict__ hrow = h + (size_t)node * DD;
    float a0 = brv0, a1 = brv1, a2 = brv2, a3 = brv3;
#pragma unroll 8
    for (int k = 0; k < 64; ++k) {
      const float hk = hrow[k];            // lane-uniform -> scalar broadcast
      const bf16* wp = &Ws[k * 256 + lane * 4];
      a0 += hk * (float)wp[0];
      a1 += hk * (float)wp[1];
      a2 += hk * (float)wp[2];
      a3 += hk * (float)wp[3];
    }
    f32x4 o = {a0, a1, a2, a3};
    float* ob = out + (size_t)node * 1024 + lane * 4;   // 4 token rows contiguous
#pragma unroll
    for (int rep = 0; rep < 4; ++rep)
      *reinterpret_cast<f32x4*>(ob + rep * 256) = o;
  }
}

extern "C" void kernel_launch(void* const* d_in, const int* in_sizes, int n_in,
                              void* d_out, int out_size, void* d_ws, size_t ws_size,
                              hipStream_t stream) {
  const int*   x   = (const int*)d_in[0];
  const float* emb = (const float*)d_in[1];
  const float* wm1 = (const float*)d_in[2];
  const float* bm1 = (const float*)d_in[3];
  const float* wm2 = (const float*)d_in[4];
  const float* bm2 = (const float*)d_in[5];
  const float* wu1 = (const float*)d_in[6];
  const float* bu1 = (const float*)d_in[7];
  const float* wu2 = (const float*)d_in[8];
  const float* bu2 = (const float*)d_in[9];
  const float* lng = (const float*)d_in[10];
  const float* lnb = (const float*)d_in[11];
  const float* wr  = (const float*)d_in[12];
  const float* br  = (const float*)d_in[13];
  float* out = (float*)d_out;

  char* ws = (char*)d_ws;
  float* ha = (float*)ws;                                   // 16 MB
  float* hb = (float*)(ws + (size_t)RTOT * DD * 4);         // 16 MB

  hipLaunchKernelGGL(k_embed, dim3(16384), dim3(256), 0, stream, x, emb, ha);
  hipLaunchKernelGGL(k_round_m, dim3(1024), dim3(256), 0, stream,
                     ha, hb, wm1, bm1, wm2, bm2, wu1, bu1, wu2, bu2, lng, lnb);
  hipLaunchKernelGGL(k_round_m, dim3(1024), dim3(256), 0, stream,
                     hb, ha, wm1, bm1, wm2, bm2, wu1, bu1, wu2, bu2, lng, lnb);
  hipLaunchKernelGGL(k_round_m, dim3(1024), dim3(256), 0, stream,
                     ha, hb, wm1, bm1, wm2, bm2, wu1, bu1, wu2, bu2, lng, lnb);
  hipLaunchKernelGGL(k_readout, dim3(1024), dim3(256), 0, stream, hb, wr, br, out);
}

// Round 4
// 139.112 us; speedup vs baseline: 4.4290x; 1.1165x over previous
//
#include <hip/hip_runtime.h>
#include <hip/hip_bf16.h>
#include <math.h>

#define DD 64
#define NPB 2048          // nodes per batch (N)
#define RTOT 65536        // total node rows B*N
#define W1S 136           // padded row stride, [64][128] tiles (272 B, 16B-aligned)
#define W2S 72            // padded row stride, [64][64] tiles (144 B, 16B-aligned)

typedef __bf16 bf16;
typedef bf16 bf16x8 __attribute__((ext_vector_type(8)));
typedef float f32x4 __attribute__((ext_vector_type(4)));

#define COMPILER_FENCE() asm volatile("" ::: "memory")

__device__ __forceinline__ f32x4 mfma16(bf16x8 a, bf16x8 b, f32x4 c) {
  return __builtin_amdgcn_mfma_f32_16x16x32_bf16(a, b, c, 0, 0, 0);
}

__device__ __forceinline__ float gelu_exact(float x) {
  return 0.5f * x * (1.0f + erff(x * 0.70710678118654752f));
}

__device__ __forceinline__ bf16x8 cvt8(const float* p) {
  f32x4 a = *reinterpret_cast<const f32x4*>(p);
  f32x4 b = *reinterpret_cast<const f32x4*>(p + 4);
  bf16x8 r;
  r[0] = (bf16)a[0]; r[1] = (bf16)a[1]; r[2] = (bf16)a[2]; r[3] = (bf16)a[3];
  r[4] = (bf16)b[0]; r[5] = (bf16)b[1]; r[6] = (bf16)b[2]; r[7] = (bf16)b[3];
  return r;
}

__device__ __forceinline__ bf16x8 zero8() {
  bf16x8 z = {(bf16)0.f, (bf16)0.f, (bf16)0.f, (bf16)0.f,
              (bf16)0.f, (bf16)0.f, (bf16)0.f, (bf16)0.f};
  return z;
}

// ---------------- embedding + patch mean ----------------
__global__ void __launch_bounds__(256) k_embed(const int* __restrict__ x,
                                               const float* __restrict__ emb,
                                               float* __restrict__ h) {
  int gid = blockIdx.x * 256 + threadIdx.x;
  int row = gid >> 6, d = gid & 63;
  const int* xp = x + row * 4;
  float s = 0.f;
#pragma unroll
  for (int p = 0; p < 4; ++p) s += emb[xp[p] * DD + d];
  h[row * DD + d] = s * 0.25f;
}

// ---- prep: convert+transpose round weights into d_out scratch (bf16) ----
// Wsc layout: [0:8192) wm1t[n][k], [8192:16384) wu1t, [16384:20480) wm2t,
// [20480:24576) wu2t. Safe in d_out: rounds finish before k_readout writes it.
__global__ void __launch_bounds__(256) k_prep(const float* __restrict__ wm1,
                                              const float* __restrict__ wm2,
                                              const float* __restrict__ wu1,
                                              const float* __restrict__ wu2,
                                              bf16* __restrict__ Wsc) {
  int gid = blockIdx.x * 256 + threadIdx.x;   // 96 * 256 = 24576
  if (gid < 8192) {
    int n = gid >> 7, k = gid & 127;
    Wsc[gid] = (bf16)wm1[k * 64 + n];
  } else if (gid < 16384) {
    int j = gid - 8192, n = j >> 7, k = j & 127;
    Wsc[gid] = (bf16)wu1[k * 64 + n];
  } else if (gid < 20480) {
    int j = gid - 16384, n = j >> 6, k = j & 63;
    Wsc[gid] = (bf16)wm2[k * 64 + n];
  } else {
    int j = gid - 20480, n = j >> 6, k = j & 63;
    Wsc[gid] = (bf16)wu2[k * 64 + n];
  }
}

// ---- prep readout weights: wrt[v][k] = wr[k][v], bf16, into ha (dead) ----
__global__ void __launch_bounds__(256) k_prep_r(const float* __restrict__ wr,
                                                bf16* __restrict__ wrt) {
  int gid = blockIdx.x * 256 + threadIdx.x;   // 64 * 256 = 16384
  int v = gid >> 6, k = gid & 63;
  wrt[gid] = (bf16)wr[k * 256 + v];
}

// ---------------- one message-passing round (MFMA) ----------------
__global__ void __launch_bounds__(256) k_round_m(const float* __restrict__ hin,
                                                 float* __restrict__ hout,
                                                 const bf16* __restrict__ Wsc,
                                                 const float* __restrict__ bm1,
                                                 const float* __restrict__ bm2,
                                                 const float* __restrict__ bu1,
                                                 const float* __restrict__ bu2,
                                                 const float* __restrict__ lng,
                                                 const float* __restrict__ lnb) {
  __shared__ bf16 W1[2][64 * W1S];  // [0]=wm1t, [1]=wu1t  ([n][k], padded)
  __shared__ bf16 Ms[64 * W2S];     // msgs
  __shared__ bf16 Hs[64 * W2S];     // GELU intermediates

  const int tid = threadIdx.x;
  const int lane = tid & 63;
  const int wv = tid >> 6;
  const int l15 = lane & 15;
  const int lhi = lane >> 4;
  const int rowbase = blockIdx.x * 64;

  // ---- stage W1 (both) via vector copies: 8 iters/thread ----
  for (int i = tid; i < 2048; i += 256) {
    int buf = i >> 10, idx = i & 1023;
    int n = idx >> 4, g = (idx & 15) * 8;
    *reinterpret_cast<bf16x8*>(&W1[buf][n * W1S + g]) =
        *reinterpret_cast<const bf16x8*>(Wsc + buf * 8192 + n * 128 + g);
  }
  // ---- wm2/wu2 B-fragments in registers ----
  bf16x8 fm2[4][2], fu2[4][2];
#pragma unroll
  for (int ct = 0; ct < 4; ++ct)
#pragma unroll
    for (int kt = 0; kt < 2; ++kt) {
      int off = (ct * 16 + l15) * 64 + kt * 32 + lhi * 8;
      fm2[ct][kt] = *reinterpret_cast<const bf16x8*>(Wsc + 16384 + off);
      fu2[ct][kt] = *reinterpret_cast<const bf16x8*>(Wsc + 20480 + off);
    }
  float bm1v[4], bm2v[4], bu1v[4], bu2v[4], lngv[4], lnbv[4];
#pragma unroll
  for (int ct = 0; ct < 4; ++ct) {
    int c = ct * 16 + l15;
    bm1v[ct] = bm1[c]; bm2v[ct] = bm2[c];
    bu1v[ct] = bu1[c]; bu2v[ct] = bu2[c];
    lngv[ct] = lng[c]; lnbv[ct] = lnb[c];
  }
  __syncthreads();

  const int lrow = wv * 16 + l15;
  const int grow = rowbase + lrow;
  const float* hrow = hin + (size_t)grow * DD;

  bf16x8 ah0 = cvt8(hrow + lhi * 8);
  bf16x8 ah1 = cvt8(hrow + 32 + lhi * 8);
  bf16x8 al0 = zero8(), al1 = zero8();
  if ((grow & (NPB - 1)) != 0) {
    al0 = cvt8(hrow - DD + lhi * 8);
    al1 = cvt8(hrow - DD + 32 + lhi * 8);
  }

  f32x4 acc[4];
  const f32x4 fz = {0.f, 0.f, 0.f, 0.f};

  // ======== GEMM1: [h,left] @ wm1 (K=128) -> GELU -> Hs ========
#pragma unroll
  for (int ct = 0; ct < 4; ++ct) acc[ct] = fz;
#pragma unroll
  for (int ct = 0; ct < 4; ++ct) {
    const bf16* wb = &W1[0][(ct * 16 + l15) * W1S];
    acc[ct] = mfma16(ah0, *reinterpret_cast<const bf16x8*>(wb + lhi * 8), acc[ct]);
    acc[ct] = mfma16(ah1, *reinterpret_cast<const bf16x8*>(wb + 32 + lhi * 8), acc[ct]);
    acc[ct] = mfma16(al0, *reinterpret_cast<const bf16x8*>(wb + 64 + lhi * 8), acc[ct]);
    acc[ct] = mfma16(al1, *reinterpret_cast<const bf16x8*>(wb + 96 + lhi * 8), acc[ct]);
  }
#pragma unroll
  for (int ct = 0; ct < 4; ++ct)
#pragma unroll
    for (int r = 0; r < 4; ++r) {
      float g = gelu_exact(acc[ct][r] + bm1v[ct]);
      Hs[(wv * 16 + lhi * 4 + r) * W2S + ct * 16 + l15] = (bf16)g;  // own rows
    }
  COMPILER_FENCE();

  // ======== GEMM2: g @ wm2 (K=64) -> msgs -> Ms ========
#pragma unroll
  for (int ct = 0; ct < 4; ++ct) acc[ct] = fz;
  {
    bf16x8 g0 = *reinterpret_cast<const bf16x8*>(&Hs[lrow * W2S + lhi * 8]);
    bf16x8 g1 = *reinterpret_cast<const bf16x8*>(&Hs[lrow * W2S + 32 + lhi * 8]);
#pragma unroll
    for (int ct = 0; ct < 4; ++ct) {
      acc[ct] = mfma16(g0, fm2[ct][0], acc[ct]);
      acc[ct] = mfma16(g1, fm2[ct][1], acc[ct]);
    }
  }
#pragma unroll
  for (int ct = 0; ct < 4; ++ct)
#pragma unroll
    for (int r = 0; r < 4; ++r)
      Ms[(wv * 16 + lhi * 4 + r) * W2S + ct * 16 + l15] =
          (bf16)(acc[ct][r] + bm2v[ct]);
  COMPILER_FENCE();

  // ======== GEMM3: [h,msgs] @ wu1 (K=128) -> GELU -> Hs ========
#pragma unroll
  for (int ct = 0; ct < 4; ++ct) acc[ct] = fz;
  {
    bf16x8 m0 = *reinterpret_cast<const bf16x8*>(&Ms[lrow * W2S + lhi * 8]);
    bf16x8 m1 = *reinterpret_cast<const bf16x8*>(&Ms[lrow * W2S + 32 + lhi * 8]);
#pragma unroll
    for (int ct = 0; ct < 4; ++ct) {
      const bf16* wb = &W1[1][(ct * 16 + l15) * W1S];
      acc[ct] = mfma16(ah0, *reinterpret_cast<const bf16x8*>(wb + lhi * 8), acc[ct]);
      acc[ct] = mfma16(ah1, *reinterpret_cast<const bf16x8*>(wb + 32 + lhi * 8), acc[ct]);
      acc[ct] = mfma16(m0, *reinterpret_cast<const bf16x8*>(wb + 64 + lhi * 8), acc[ct]);
      acc[ct] = mfma16(m1, *reinterpret_cast<const bf16x8*>(wb + 96 + lhi * 8), acc[ct]);
    }
  }
  COMPILER_FENCE();
#pragma unroll
  for (int ct = 0; ct < 4; ++ct)
#pragma unroll
    for (int r = 0; r < 4; ++r) {
      float g = gelu_exact(acc[ct][r] + bu1v[ct]);
      Hs[(wv * 16 + lhi * 4 + r) * W2S + ct * 16 + l15] = (bf16)g;
    }
  COMPILER_FENCE();

  // ======== GEMM4: gu @ wu2 (K=64) -> upd; residual + LN ========
#pragma unroll
  for (int ct = 0; ct < 4; ++ct) acc[ct] = fz;
  {
    bf16x8 u0 = *reinterpret_cast<const bf16x8*>(&Hs[lrow * W2S + lhi * 8]);
    bf16x8 u1 = *reinterpret_cast<const bf16x8*>(&Hs[lrow * W2S + 32 + lhi * 8]);
#pragma unroll
    for (int ct = 0; ct < 4; ++ct) {
      acc[ct] = mfma16(u0, fu2[ct][0], acc[ct]);
      acc[ct] = mfma16(u1, fu2[ct][1], acc[ct]);
    }
  }

  float xv[4][4];
#pragma unroll
  for (int ct = 0; ct < 4; ++ct)
#pragma unroll
    for (int r = 0; r < 4; ++r) {
      int row = rowbase + wv * 16 + lhi * 4 + r;
      xv[ct][r] = acc[ct][r] + bu2v[ct] + hin[row * DD + ct * 16 + l15];
    }
  float s1[4], s2[4];
#pragma unroll
  for (int r = 0; r < 4; ++r) {
    s1[r] = 0.f; s2[r] = 0.f;
#pragma unroll
    for (int ct = 0; ct < 4; ++ct) {
      s1[r] += xv[ct][r];
      s2[r] += xv[ct][r] * xv[ct][r];
    }
  }
#pragma unroll
  for (int off = 1; off < 16; off <<= 1)
#pragma unroll
    for (int r = 0; r < 4; ++r) {
      s1[r] += __shfl_xor(s1[r], off);
      s2[r] += __shfl_xor(s2[r], off);
    }
#pragma unroll
  for (int r = 0; r < 4; ++r) {
    float mu = s1[r] * 0.015625f;
    float var = s2[r] * 0.015625f - mu * mu;
    float rstd = rsqrtf(var + 1e-5f);
    int row = rowbase + wv * 16 + lhi * 4 + r;
#pragma unroll
    for (int ct = 0; ct < 4; ++ct)
      hout[row * DD + ct * 16 + l15] =
          (xv[ct][r] - mu) * rstd * lngv[ct] + lnbv[ct];
  }
}

// ---------------- readout (MFMA, swapped operands) ----------------
// C = wrt-tile @ h-tile: C[col=lane&15]=node, row = v within tile.
// Each lane ends with 16x f32x4 of 4 CONSECUTIVE v for ONE node -> direct
// f32x4 stores, replicated to the node's 4 contiguous token rows.
__global__ void __launch_bounds__(256) k_readout(const float* __restrict__ h,
                                                 const bf16* __restrict__ wrt,
                                                 const float* __restrict__ br,
                                                 float* __restrict__ out) {
  __shared__ bf16 Wt[256 * W2S];  // wrt padded: [v][k], 36864 B
  const int tid = threadIdx.x, lane = tid & 63, wv = tid >> 6;
  const int l15 = lane & 15, lhi = lane >> 4;

  for (int i = tid; i < 2048; i += 256) {
    int v = i >> 3, g = (i & 7) * 8;
    *reinterpret_cast<bf16x8*>(&Wt[v * W2S + g]) =
        *reinterpret_cast<const bf16x8*>(wrt + v * 64 + g);
  }
  f32x4 brv[16];
#pragma unroll
  for (int vt = 0; vt < 16; ++vt)
    brv[vt] = *reinterpret_cast<const f32x4*>(br + vt * 16 + lhi * 4);
  __syncthreads();

  const int node = blockIdx.x * 64 + wv * 16 + l15;
  const float* hrow = h + (size_t)node * DD;
  bf16x8 b0 = cvt8(hrow + lhi * 8);         // B-frag: n=node, k-chunks
  bf16x8 b1 = cvt8(hrow + 32 + lhi * 8);

  f32x4 acc[16];
  const f32x4 fz = {0.f, 0.f, 0.f, 0.f};
#pragma unroll
  for (int vt = 0; vt < 16; ++vt) {
    const bf16* wb = &Wt[(vt * 16 + l15) * W2S];
    bf16x8 a0 = *reinterpret_cast<const bf16x8*>(wb + lhi * 8);
    bf16x8 a1 = *reinterpret_cast<const bf16x8*>(wb + 32 + lhi * 8);
    acc[vt] = mfma16(a0, b0, fz);
    acc[vt] = mfma16(a1, b1, acc[vt]);
  }

  float* ob = out + (size_t)node * 1024 + lhi * 4;
#pragma unroll
  for (int vt = 0; vt < 16; ++vt) {
    f32x4 val = acc[vt] + brv[vt];
    float* p = ob + vt * 16;
#pragma unroll
    for (int rep = 0; rep < 4; ++rep)
      *reinterpret_cast<f32x4*>(p + rep * 256) = val;
  }
}

extern "C" void kernel_launch(void* const* d_in, const int* in_sizes, int n_in,
                              void* d_out, int out_size, void* d_ws, size_t ws_size,
                              hipStream_t stream) {
  const int*   x   = (const int*)d_in[0];
  const float* emb = (const float*)d_in[1];
  const float* wm1 = (const float*)d_in[2];
  const float* bm1 = (const float*)d_in[3];
  const float* wm2 = (const float*)d_in[4];
  const float* bm2 = (const float*)d_in[5];
  const float* wu1 = (const float*)d_in[6];
  const float* bu1 = (const float*)d_in[7];
  const float* wu2 = (const float*)d_in[8];
  const float* bu2 = (const float*)d_in[9];
  const float* lng = (const float*)d_in[10];
  const float* lnb = (const float*)d_in[11];
  const float* wr  = (const float*)d_in[12];
  const float* br  = (const float*)d_in[13];
  float* out = (float*)d_out;

  char* ws = (char*)d_ws;
  float* ha = (float*)ws;                                   // 16 MB
  float* hb = (float*)(ws + (size_t)RTOT * DD * 4);         // 16 MB
  bf16* Wsc = (bf16*)d_out;      // 48 KB round-weight scratch (dead by readout)
  bf16* wrt = (bf16*)ha;         // 32 KB readout weights (ha dead after round 3)

  hipLaunchKernelGGL(k_prep, dim3(96), dim3(256), 0, stream,
                     wm1, wm2, wu1, wu2, Wsc);
  hipLaunchKernelGGL(k_embed, dim3(16384), dim3(256), 0, stream, x, emb, ha);
  hipLaunchKernelGGL(k_round_m, dim3(1024), dim3(256), 0, stream,
                     ha, hb, Wsc, bm1, bm2, bu1, bu2, lng, lnb);
  hipLaunchKernelGGL(k_round_m, dim3(1024), dim3(256), 0, stream,
                     hb, ha, Wsc, bm1, bm2, bu1, bu2, lng, lnb);
  hipLaunchKernelGGL(k_round_m, dim3(1024), dim3(256), 0, stream,
                     ha, hb, Wsc, bm1, bm2, bu1, bu2, lng, lnb);
  hipLaunchKernelGGL(k_prep_r, dim3(64), dim3(256), 0, stream, wr, wrt);
  hipLaunchKernelGGL(k_readout, dim3(1024), dim3(256), 0, stream, hb, wrt, br, out);
}